// Round 1
// baseline (152.088 us; speedup 1.0000x reference)
//
#include <hip/hip_runtime.h>

// CtxAttention: additive attention (Bahdanau).
//   e[n,t]  = sum_a w_v[a] * tanh( enc_pad[n,t,:]·W_enc[a,:] + b_enc[a] + dec_prev[n,:]·W_dec[a,:] )
//   ali     = softmax_t(mask(e));  ctx[n,:] = sum_t ali[n,t] * enc_pad[n,t,:]
// N=32, TI=2000, ED=AD=512.  Main GEMM (64000x512 @ 512x512) done in f16 MFMA, fp32 accum.

#define NB  32
#define TI  2000
#define ED  512
#define AD  512
#define M_TOT (NB * TI)          // 64000
#define NSPLIT 20                // t-splits for ctx partials
#define TCHUNK (TI / NSPLIT)     // 100

using f16x8 = __attribute__((ext_vector_type(8))) _Float16;
using f32x4 = __attribute__((ext_vector_type(4))) float;

__device__ __forceinline__ float fast_tanh(float s) {
    s = fminf(fmaxf(s, -15.f), 15.f);
    float t = __expf(2.f * s);
    return __fdividef(t - 1.f, t + 1.f);
}

// ---------------- Kernel 1: db[n][a] = dec_prev[n,:]·W_dec[a,:] + b_enc[a] ----------------
__global__ void k_decdb(const float* __restrict__ dec_prev,
                        const float* __restrict__ W_dec,
                        const float* __restrict__ b_enc,
                        float* __restrict__ db) {
    int n = blockIdx.x;
    __shared__ float xd[ED];
    for (int k = threadIdx.x; k < ED; k += 256) xd[k] = dec_prev[n * ED + k];
    __syncthreads();
    for (int a = threadIdx.x; a < AD; a += 256) {
        const float* wr = W_dec + (size_t)a * ED;
        float s = 0.f;
#pragma unroll 8
        for (int k = 0; k < ED; k += 4) {
            float4 w = *(const float4*)(wr + k);
            s += xd[k] * w.x + xd[k + 1] * w.y + xd[k + 2] * w.z + xd[k + 3] * w.w;
        }
        db[n * AD + a] = s + b_enc[a];
    }
}

// ---------------- Kernel 2: fused score GEMM + tanh + w_v reduction ----------------
// Grid: (500 m-tiles, 4 a-tiles), block 256 (4 waves as 2x2, each wave 64x64 output).
// e_part[p][m] = sum over a in [p*128,(p+1)*128) of w_v[a]*tanh(X[m,:]·W[a,:] + db[n(m),a])
__launch_bounds__(256, 2)
__global__ void k_score(const float* __restrict__ X,     // enc_pad as (64000 x 512)
                        const float* __restrict__ W,     // W_enc (512 x 512)
                        const float* __restrict__ db,    // (32 x 512)
                        const float* __restrict__ wv,    // (512)
                        float* __restrict__ e_part) {    // (4 x 64000)
    __shared__ alignas(16) _Float16 Xs[128][72];  // +8 halves pad -> conflict-free-ish
    __shared__ alignas(16) _Float16 Ws[128][72];
    __shared__ float e_red[2][128];

    const int tid  = threadIdx.x;
    const int lane = tid & 63;
    const int wid  = tid >> 6;
    const int wr   = wid >> 1;      // wave row (0..1) -> rows wr*64..+64
    const int wc   = wid & 1;       // wave col (0..1) -> cols wc*64..+64
    const int m0   = blockIdx.x * 128;
    const int a0   = blockIdx.y * 128;

    f32x4 acc[4][4];
#pragma unroll
    for (int rb = 0; rb < 4; ++rb) {
#pragma unroll
        for (int cb = 0; cb < 4; ++cb) acc[rb][cb] = (f32x4){0.f, 0.f, 0.f, 0.f};
    }

    const int lr = lane & 15;
    const int lk = (lane >> 4) << 3;   // k-offset of this lane's 8-elem fragment slice

    for (int kt = 0; kt < ED; kt += 64) {
        // stage 128x64 of X and W, converting fp32 -> fp16
#pragma unroll
        for (int i = 0; i < 4; ++i) {
            int idx = tid + i * 256;           // 0..1023
            int r = idx >> 3;                  // 0..127
            int c = (idx & 7) << 3;            // 0..56
            const float* gx = X + (size_t)(m0 + r) * ED + kt + c;
            float4 x0 = *(const float4*)gx;
            float4 x1 = *(const float4*)(gx + 4);
            f16x8 hx;
            hx[0] = (_Float16)x0.x; hx[1] = (_Float16)x0.y;
            hx[2] = (_Float16)x0.z; hx[3] = (_Float16)x0.w;
            hx[4] = (_Float16)x1.x; hx[5] = (_Float16)x1.y;
            hx[6] = (_Float16)x1.z; hx[7] = (_Float16)x1.w;
            *(f16x8*)&Xs[r][c] = hx;
            const float* gw = W + (size_t)(a0 + r) * ED + kt + c;
            float4 w0 = *(const float4*)gw;
            float4 w1 = *(const float4*)(gw + 4);
            f16x8 hw;
            hw[0] = (_Float16)w0.x; hw[1] = (_Float16)w0.y;
            hw[2] = (_Float16)w0.z; hw[3] = (_Float16)w0.w;
            hw[4] = (_Float16)w1.x; hw[5] = (_Float16)w1.y;
            hw[6] = (_Float16)w1.z; hw[7] = (_Float16)w1.w;
            *(f16x8*)&Ws[r][c] = hw;
        }
        __syncthreads();

#pragma unroll
        for (int kb = 0; kb < 64; kb += 32) {
            f16x8 aF[4], bF[4];
#pragma unroll
            for (int rb = 0; rb < 4; ++rb)
                aF[rb] = *(const f16x8*)&Xs[wr * 64 + rb * 16 + lr][kb + lk];
#pragma unroll
            for (int cb = 0; cb < 4; ++cb)
                bF[cb] = *(const f16x8*)&Ws[wc * 64 + cb * 16 + lr][kb + lk];
#pragma unroll
            for (int rb = 0; rb < 4; ++rb) {
#pragma unroll
                for (int cb = 0; cb < 4; ++cb)
                    acc[rb][cb] = __builtin_amdgcn_mfma_f32_16x16x32_f16(
                        aF[rb], bF[cb], acc[rb][cb], 0, 0, 0);
            }
        }
        __syncthreads();
    }

    // epilogue: v = tanh(acc + db)*w_v, reduce over the 128 a-cols of this block
    const int lg = lane >> 4;
    float wvv[4];
#pragma unroll
    for (int cb = 0; cb < 4; ++cb) wvv[cb] = wv[a0 + wc * 64 + cb * 16 + lr];

#pragma unroll
    for (int rb = 0; rb < 4; ++rb) {
#pragma unroll
        for (int i = 0; i < 4; ++i) {
            int row_local = wr * 64 + rb * 16 + lg * 4 + i;  // C/D layout: row=(lane>>4)*4+reg
            int m = m0 + row_local;
            int n = m / TI;
            const float* dbp = db + (size_t)n * AD + a0 + wc * 64;
            float rs = 0.f;
#pragma unroll
            for (int cb = 0; cb < 4; ++cb) {
                float s = acc[rb][cb][i] + dbp[cb * 16 + lr];  // col = lane&15
                rs += fast_tanh(s) * wvv[cb];
            }
            rs += __shfl_xor(rs, 1);
            rs += __shfl_xor(rs, 2);
            rs += __shfl_xor(rs, 4);
            rs += __shfl_xor(rs, 8);
            if (lr == 0) e_red[wc][row_local] = rs;
        }
    }
    __syncthreads();
    if (tid < 128)
        e_part[(size_t)blockIdx.y * M_TOT + m0 + tid] = e_red[0][tid] + e_red[1][tid];
}

// ---------------- Kernel 3: masked softmax over t, per n ----------------
__global__ void k_softmax(const float* __restrict__ e_part,
                          const int* __restrict__ enc_len,
                          float* __restrict__ ali) {
    int n = blockIdx.x;
    int len = enc_len[n];
    __shared__ float se[TI];
    __shared__ float redm[4];
    __shared__ float reds[4];
    int tid = threadIdx.x;
    int lane = tid & 63, wid = tid >> 6;

    for (int t = tid; t < TI; t += 256) {
        se[t] = e_part[n * TI + t] + e_part[M_TOT + n * TI + t] +
                e_part[2 * M_TOT + n * TI + t] + e_part[3 * M_TOT + n * TI + t];
    }
    __syncthreads();

    float mx = -1e30f;
    for (int t = tid; t < len; t += 256) mx = fmaxf(mx, se[t]);
#pragma unroll
    for (int o = 32; o >= 1; o >>= 1) mx = fmaxf(mx, __shfl_xor(mx, o));
    if (lane == 0) redm[wid] = mx;
    __syncthreads();
    mx = fmaxf(fmaxf(redm[0], redm[1]), fmaxf(redm[2], redm[3]));

    float sm = 0.f;
    for (int t = tid; t < len; t += 256) {
        float ex = __expf(se[t] - mx);
        se[t] = ex;
        sm += ex;
    }
#pragma unroll
    for (int o = 32; o >= 1; o >>= 1) sm += __shfl_xor(sm, o);
    if (lane == 0) reds[wid] = sm;
    __syncthreads();
    float inv = 1.f / (reds[0] + reds[1] + reds[2] + reds[3]);

    for (int t = tid; t < TI; t += 256)
        ali[n * TI + t] = (t < len) ? se[t] * inv : 0.f;
}

// ---------------- Kernel 4: ctx partials over t-chunks ----------------
__global__ void k_ctxpart(const float* __restrict__ enc,
                          const float* __restrict__ ali,
                          float* __restrict__ cpart) {
    int s = blockIdx.x;   // 0..NSPLIT-1
    int n = blockIdx.y;   // 0..31
    int d0 = threadIdx.x * 2;
    const float* base = enc + ((size_t)n * TI + s * TCHUNK) * ED + d0;
    const float* ap = ali + n * TI + s * TCHUNK;
    float ax = 0.f, ay = 0.f;
#pragma unroll 4
    for (int t = 0; t < TCHUNK; ++t) {
        float a = ap[t];
        float2 v = *(const float2*)(base + (size_t)t * ED);
        ax = fmaf(a, v.x, ax);
        ay = fmaf(a, v.y, ay);
    }
    float2 r; r.x = ax; r.y = ay;
    *(float2*)&cpart[((size_t)(n * NSPLIT + s)) * ED + d0] = r;
}

// ---------------- Kernel 5: reduce ctx partials ----------------
__global__ void k_ctxred(const float* __restrict__ cpart, float* __restrict__ ctx) {
    int n = blockIdx.x;
    for (int d = threadIdx.x; d < ED; d += 256) {
        float sum = 0.f;
#pragma unroll
        for (int s = 0; s < NSPLIT; ++s) sum += cpart[((size_t)(n * NSPLIT + s)) * ED + d];
        ctx[(size_t)n * ED + d] = sum;
    }
}

extern "C" void kernel_launch(void* const* d_in, const int* in_sizes, int n_in,
                              void* d_out, int out_size, void* d_ws, size_t ws_size,
                              hipStream_t stream) {
    const float* enc_pad  = (const float*)d_in[0];
    const int*   enc_len  = (const int*)d_in[1];
    const float* dec_prev = (const float*)d_in[2];
    // d_in[3] = ali_prev (unused by reference)
    const float* W_enc    = (const float*)d_in[4];
    const float* b_enc    = (const float*)d_in[5];
    const float* W_dec    = (const float*)d_in[6];
    const float* w_v      = (const float*)d_in[7];

    float* out = (float*)d_out;
    float* ali = out;              // 64000 floats
    float* ctx = out + M_TOT;      // 16384 floats

    float* ws     = (float*)d_ws;
    float* db     = ws;                          // 32*512        = 16384
    float* e_part = ws + NB * AD;                // 4*64000       = 256000
    float* cpart  = e_part + 4 * M_TOT;          // 32*20*512     = 327680

    hipLaunchKernelGGL(k_decdb,   dim3(NB), dim3(256), 0, stream, dec_prev, W_dec, b_enc, db);
    hipLaunchKernelGGL(k_score,   dim3(M_TOT / 128, AD / 128), dim3(256), 0, stream,
                       enc_pad, W_enc, db, w_v, e_part);
    hipLaunchKernelGGL(k_softmax, dim3(NB), dim3(256), 0, stream, e_part, enc_len, ali);
    hipLaunchKernelGGL(k_ctxpart, dim3(NSPLIT, NB), dim3(256), 0, stream, enc_pad, ali, cpart);
    hipLaunchKernelGGL(k_ctxred,  dim3(NB), dim3(256), 0, stream, cpart, ctx);
}

// Round 2
// 146.958 us; speedup vs baseline: 1.0349x; 1.0349x over previous
//
#include <hip/hip_runtime.h>
#include <stdint.h>

// CtxAttention: additive attention (Bahdanau).
//   e[n,t]  = sum_a w_v[a] * tanh( enc_pad[n,t,:]·W_enc[a,:] + b_enc[a] + dec_prev[n,:]·W_dec[a,:] )
//   ali     = softmax_t(mask(e));  ctx[n,:] = sum_t ali[n,t] * enc_pad[n,t,:]
// Main GEMM (64000x512 @ 512x512) in f16 MFMA. Strategy: pre-convert X,W to a
// tiled + XOR-swizzled fp16 buffer once, then m97-style GEMM with
// global_load_lds(16B) staging and conflict-free swizzled ds_read_b128.

#define NB  32
#define TI  2000
#define ED  512
#define AD  512
#define M_TOT (NB * TI)          // 64000
#define NSPLIT 20
#define TCHUNK (TI / NSPLIT)     // 100
#define MT  500                  // m-tiles of 128
#define KT  8                    // k-tiles of 64
#define TILE_BYTES  16384        // 128 rows x 64 halves x 2B
#define TILE_HALVES 8192

using f16x8 = __attribute__((ext_vector_type(8))) _Float16;
using f32x4 = __attribute__((ext_vector_type(4))) float;

// swizzle: byte offset within a 128x64-half tile; row r, byte-col c2 (16B aligned)
//   so = (r*128 + c2) ^ ((r&7)<<4)  -> spreads the 16-row fragment column reads
//   across all 32 banks (2-way aliasing only, which is free per m136).
__device__ __forceinline__ int swz(int r, int c2) { return (r * 128 + c2) ^ ((r & 7) << 4); }

#define GLD16(g, l)                                                     \
    __builtin_amdgcn_global_load_lds(                                   \
        (const __attribute__((address_space(1))) void*)(g),             \
        (__attribute__((address_space(3))) void*)(l), 16, 0, 0)

__device__ __forceinline__ float fast_tanh(float s) {
    s = fminf(fmaxf(s, -15.f), 15.f);
    float t = __expf(2.f * s);
    return __fdividef(t - 1.f, t + 1.f);
}

// ---------------- Kernel 0: convert enc_pad / W_enc -> tiled swizzled fp16 ----------------
// X tiles: bx in [0, 4000): mt = bx>>3, kt = bx&7.  W tiles: bx-4000 = at*8+kt.
__global__ void k_convert(const float* __restrict__ enc, const float* __restrict__ Wenc,
                          _Float16* __restrict__ X16, _Float16* __restrict__ W16) {
    int bx = blockIdx.x;
    const float* src;
    char* dstb;
    if (bx < MT * KT) {
        int mt = bx >> 3, kt = bx & 7;
        src  = enc + (size_t)mt * 128 * ED + kt * 64;
        dstb = (char*)(X16 + (size_t)bx * TILE_HALVES);
    } else {
        int wt = bx - MT * KT;
        int at = wt >> 3, kt = wt & 7;
        src  = Wenc + (size_t)at * 128 * ED + kt * 64;
        dstb = (char*)(W16 + (size_t)wt * TILE_HALVES);
    }
    int tid = threadIdx.x;
#pragma unroll
    for (int i = 0; i < 4; ++i) {
        int o  = i * 4096 + tid * 16;  // logical byte offset in tile
        int r  = o >> 7;               // row 0..127
        int c2 = o & 127;              // byte col (multiple of 16)
        const float* s = src + (size_t)r * ED + (c2 >> 1);
        float4 a = *(const float4*)s;
        float4 b = *(const float4*)(s + 4);
        f16x8 h;
        h[0] = (_Float16)a.x; h[1] = (_Float16)a.y; h[2] = (_Float16)a.z; h[3] = (_Float16)a.w;
        h[4] = (_Float16)b.x; h[5] = (_Float16)b.y; h[6] = (_Float16)b.z; h[7] = (_Float16)b.w;
        *(f16x8*)(dstb + swz(r, c2)) = h;
    }
}

// ---------------- Kernel 1: db[n][a] = dec_prev[n,:]·W_dec[a,:] + b_enc[a] ----------------
__global__ void k_decdb(const float* __restrict__ dec_prev,
                        const float* __restrict__ W_dec,
                        const float* __restrict__ b_enc,
                        float* __restrict__ db) {
    int n = blockIdx.x;
    __shared__ float xd[ED];
    for (int k = threadIdx.x; k < ED; k += 256) xd[k] = dec_prev[n * ED + k];
    __syncthreads();
    for (int a = threadIdx.x; a < AD; a += 256) {
        const float* wr = W_dec + (size_t)a * ED;
        float s = 0.f;
#pragma unroll 8
        for (int k = 0; k < ED; k += 4) {
            float4 w = *(const float4*)(wr + k);
            s += xd[k] * w.x + xd[k + 1] * w.y + xd[k + 2] * w.z + xd[k + 3] * w.w;
        }
        db[n * AD + a] = s + b_enc[a];
    }
}

// ---------------- Kernel 2: fused score GEMM (fp16 tiled inputs) ----------------
// Grid 2016 blocks; fid -> (mt, at) such that the 4 a-tiles of an m-tile land on
// one XCD (fid%8 == mt%8 with default round-robin XCD assignment) for X16 L2 reuse.
__launch_bounds__(256, 4)
__global__ void k_score(const _Float16* __restrict__ X16, const _Float16* __restrict__ W16,
                        const float* __restrict__ db, const float* __restrict__ wv,
                        float* __restrict__ e_part) {
    __shared__ alignas(16) char Xs[TILE_BYTES];
    __shared__ alignas(16) char Ws[TILE_BYTES];
    __shared__ float e_red[2][128];

    int fid = blockIdx.x;
    int g = fid >> 5, rr = fid & 31;
    int at = rr >> 3, l = rr & 7;
    int mt = g * 8 + l;
    if (mt >= MT) return;

    const int tid  = threadIdx.x;
    const int lane = tid & 63;
    const int w    = tid >> 6;
    const int wr   = w >> 1;        // wave's 64-row half
    const int wc   = w & 1;         // wave's 64-col half
    const int m0   = mt * 128;
    const int a0   = at * 128;

    const char* xbase = (const char*)(X16 + (size_t)(mt * KT) * TILE_HALVES);
    const char* wbase = (const char*)(W16 + (size_t)(at * KT) * TILE_HALVES);

    f32x4 acc[4][4];
#pragma unroll
    for (int rb = 0; rb < 4; ++rb)
#pragma unroll
        for (int cb = 0; cb < 4; ++cb) acc[rb][cb] = (f32x4){0.f, 0.f, 0.f, 0.f};

    const int lr   = lane & 15;
    const int lk2  = ((lane >> 4) << 3) * 2;   // byte col of this lane's 8-half frag slice
    const int xorv = (lr & 7) << 4;
    const int stoff = w * 1024 + lane * 16;    // staging byte offset (linear)

    for (int kt = 0; kt < KT; ++kt) {
        const char* xs = xbase + kt * TILE_BYTES + stoff;
        const char* ws = wbase + kt * TILE_BYTES + stoff;
#pragma unroll
        for (int i = 0; i < 4; ++i) {
            GLD16(xs + i * 4096, Xs + i * 4096 + w * 1024);
            GLD16(ws + i * 4096, Ws + i * 4096 + w * 1024);
        }
        __syncthreads();   // drains vmcnt -> tiles visible

#pragma unroll
        for (int kb = 0; kb < 2; ++kb) {
            f16x8 aF[4], bF[4];
#pragma unroll
            for (int rb = 0; rb < 4; ++rb) {
                int r = wr * 64 + rb * 16 + lr;
                aF[rb] = *(const f16x8*)(Xs + ((r * 128 + kb * 64 + lk2) ^ xorv));
            }
#pragma unroll
            for (int cb = 0; cb < 4; ++cb) {
                int r = wc * 64 + cb * 16 + lr;
                bF[cb] = *(const f16x8*)(Ws + ((r * 128 + kb * 64 + lk2) ^ xorv));
            }
#pragma unroll
            for (int rb = 0; rb < 4; ++rb)
#pragma unroll
                for (int cb = 0; cb < 4; ++cb)
                    acc[rb][cb] = __builtin_amdgcn_mfma_f32_16x16x32_f16(
                        aF[rb], bF[cb], acc[rb][cb], 0, 0, 0);
        }
        __syncthreads();   // everyone done reading before next stage overwrites
    }

    // epilogue: rs = sum_cols w_v * tanh(acc + db); reduce 16 cols via shfl
    const int lg = lane >> 4;
    float wvv[4];
#pragma unroll
    for (int cb = 0; cb < 4; ++cb) wvv[cb] = wv[a0 + wc * 64 + cb * 16 + lr];

#pragma unroll
    for (int rb = 0; rb < 4; ++rb) {
#pragma unroll
        for (int i = 0; i < 4; ++i) {
            int row_local = wr * 64 + rb * 16 + lg * 4 + i;  // C/D: row=(lane>>4)*4+reg
            int m = m0 + row_local;
            int n = m / TI;
            const float* dbp = db + (size_t)n * AD + a0 + wc * 64;
            float rs = 0.f;
#pragma unroll
            for (int cb = 0; cb < 4; ++cb) {
                float s = acc[rb][cb][i] + dbp[cb * 16 + lr];  // col = lane&15
                rs += fast_tanh(s) * wvv[cb];
            }
            rs += __shfl_xor(rs, 1);
            rs += __shfl_xor(rs, 2);
            rs += __shfl_xor(rs, 4);
            rs += __shfl_xor(rs, 8);
            if (lr == 0) e_red[wc][row_local] = rs;
        }
    }
    __syncthreads();
    if (tid < 128)
        e_part[(size_t)at * M_TOT + m0 + tid] = e_red[0][tid] + e_red[1][tid];
}

// ---------------- fallback fp32 GEMM (convert-in-kernel) if ws too small ----------------
__launch_bounds__(256, 2)
__global__ void k_score_fb(const float* __restrict__ X, const float* __restrict__ W,
                           const float* __restrict__ db, const float* __restrict__ wv,
                           float* __restrict__ e_part) {
    __shared__ alignas(16) _Float16 Xs[128][72];
    __shared__ alignas(16) _Float16 Ws[128][72];
    __shared__ float e_red[2][128];

    const int tid = threadIdx.x, lane = tid & 63, wid = tid >> 6;
    const int wr = wid >> 1, wc = wid & 1;
    const int m0 = blockIdx.x * 128, a0 = blockIdx.y * 128;

    f32x4 acc[4][4];
#pragma unroll
    for (int rb = 0; rb < 4; ++rb)
#pragma unroll
        for (int cb = 0; cb < 4; ++cb) acc[rb][cb] = (f32x4){0.f, 0.f, 0.f, 0.f};

    const int lr = lane & 15;
    const int lk = (lane >> 4) << 3;

    for (int kt = 0; kt < ED; kt += 64) {
#pragma unroll
        for (int i = 0; i < 4; ++i) {
            int idx = tid + i * 256, r = idx >> 3, c = (idx & 7) << 3;
            const float* gx = X + (size_t)(m0 + r) * ED + kt + c;
            float4 x0 = *(const float4*)gx, x1 = *(const float4*)(gx + 4);
            f16x8 hx;
            hx[0] = (_Float16)x0.x; hx[1] = (_Float16)x0.y; hx[2] = (_Float16)x0.z; hx[3] = (_Float16)x0.w;
            hx[4] = (_Float16)x1.x; hx[5] = (_Float16)x1.y; hx[6] = (_Float16)x1.z; hx[7] = (_Float16)x1.w;
            *(f16x8*)&Xs[r][c] = hx;
            const float* gw = W + (size_t)(a0 + r) * ED + kt + c;
            float4 w0 = *(const float4*)gw, w1 = *(const float4*)(gw + 4);
            f16x8 hw;
            hw[0] = (_Float16)w0.x; hw[1] = (_Float16)w0.y; hw[2] = (_Float16)w0.z; hw[3] = (_Float16)w0.w;
            hw[4] = (_Float16)w1.x; hw[5] = (_Float16)w1.y; hw[6] = (_Float16)w1.z; hw[7] = (_Float16)w1.w;
            *(f16x8*)&Ws[r][c] = hw;
        }
        __syncthreads();
#pragma unroll
        for (int kb = 0; kb < 64; kb += 32) {
            f16x8 aF[4], bF[4];
#pragma unroll
            for (int rb = 0; rb < 4; ++rb) aF[rb] = *(const f16x8*)&Xs[wr * 64 + rb * 16 + lr][kb + lk];
#pragma unroll
            for (int cb = 0; cb < 4; ++cb) bF[cb] = *(const f16x8*)&Ws[wc * 64 + cb * 16 + lr][kb + lk];
#pragma unroll
            for (int rb = 0; rb < 4; ++rb)
#pragma unroll
                for (int cb = 0; cb < 4; ++cb)
                    acc[rb][cb] = __builtin_amdgcn_mfma_f32_16x16x32_f16(aF[rb], bF[cb], acc[rb][cb], 0, 0, 0);
        }
        __syncthreads();
    }

    const int lg = lane >> 4;
    float wvv[4];
#pragma unroll
    for (int cb = 0; cb < 4; ++cb) wvv[cb] = wv[a0 + wc * 64 + cb * 16 + lr];
#pragma unroll
    for (int rb = 0; rb < 4; ++rb) {
#pragma unroll
        for (int i = 0; i < 4; ++i) {
            int row_local = wr * 64 + rb * 16 + lg * 4 + i;
            int m = m0 + row_local;
            int n = m / TI;
            const float* dbp = db + (size_t)n * AD + a0 + wc * 64;
            float rs = 0.f;
#pragma unroll
            for (int cb = 0; cb < 4; ++cb) {
                float s = acc[rb][cb][i] + dbp[cb * 16 + lr];
                rs += fast_tanh(s) * wvv[cb];
            }
            rs += __shfl_xor(rs, 1);
            rs += __shfl_xor(rs, 2);
            rs += __shfl_xor(rs, 4);
            rs += __shfl_xor(rs, 8);
            if (lr == 0) e_red[wc][row_local] = rs;
        }
    }
    __syncthreads();
    if (tid < 128)
        e_part[(size_t)blockIdx.y * M_TOT + m0 + tid] = e_red[0][tid] + e_red[1][tid];
}

// ---------------- Kernel 3: masked softmax over t, per n ----------------
__global__ void k_softmax(const float* __restrict__ e_part,
                          const int* __restrict__ enc_len,
                          float* __restrict__ ali) {
    int n = blockIdx.x;
    int len = enc_len[n];
    __shared__ float se[TI];
    __shared__ float redm[4];
    __shared__ float reds[4];
    int tid = threadIdx.x;
    int lane = tid & 63, wid = tid >> 6;

    for (int t = tid; t < TI; t += 256) {
        se[t] = e_part[n * TI + t] + e_part[M_TOT + n * TI + t] +
                e_part[2 * M_TOT + n * TI + t] + e_part[3 * M_TOT + n * TI + t];
    }
    __syncthreads();

    float mx = -1e30f;
    for (int t = tid; t < len; t += 256) mx = fmaxf(mx, se[t]);
#pragma unroll
    for (int o = 32; o >= 1; o >>= 1) mx = fmaxf(mx, __shfl_xor(mx, o));
    if (lane == 0) redm[wid] = mx;
    __syncthreads();
    mx = fmaxf(fmaxf(redm[0], redm[1]), fmaxf(redm[2], redm[3]));

    float sm = 0.f;
    for (int t = tid; t < len; t += 256) {
        float ex = __expf(se[t] - mx);
        se[t] = ex;
        sm += ex;
    }
#pragma unroll
    for (int o = 32; o >= 1; o >>= 1) sm += __shfl_xor(sm, o);
    if (lane == 0) reds[wid] = sm;
    __syncthreads();
    float inv = 1.f / (reds[0] + reds[1] + reds[2] + reds[3]);

    for (int t = tid; t < TI; t += 256)
        ali[n * TI + t] = (t < len) ? se[t] * inv : 0.f;
}

// ---------------- Kernel 4a: ctx partials from fp16 tiled X16 ----------------
__global__ void k_ctxpart16(const _Float16* __restrict__ X16, const float* __restrict__ ali,
                            float* __restrict__ cpart) {
    int s = blockIdx.x, n = blockIdx.y;
    int tid = threadIdx.x;
    int sub = tid >> 6;            // t-phase 0..3
    int dc  = (tid & 63) * 8;      // 8 d-cols per thread
    int ktile = dc >> 6;
    int c2 = (dc & 63) * 2;
    float acc[8] = {0.f, 0.f, 0.f, 0.f, 0.f, 0.f, 0.f, 0.f};
    for (int t = s * TCHUNK + sub; t < (s + 1) * TCHUNK; t += 4) {
        int m = n * TI + t;
        int mt2 = m >> 7, r = m & 127;
        const char* p = (const char*)(X16 + (size_t)(mt2 * KT + ktile) * TILE_HALVES);
        f16x8 v = *(const f16x8*)(p + swz(r, c2));
        float a = ali[m];
#pragma unroll
        for (int j = 0; j < 8; ++j) acc[j] = fmaf(a, (float)v[j], acc[j]);
    }
    __shared__ float red[4][ED];
#pragma unroll
    for (int j = 0; j < 8; ++j) red[sub][dc + j] = acc[j];
    __syncthreads();
    if (sub == 0) {
#pragma unroll
        for (int j = 0; j < 8; ++j) {
            float sm = red[0][dc + j] + red[1][dc + j] + red[2][dc + j] + red[3][dc + j];
            cpart[((size_t)(n * NSPLIT + s)) * ED + dc + j] = sm;
        }
    }
}

// ---------------- Kernel 4b: fp32 ctx partials (fallback) ----------------
__global__ void k_ctxpart(const float* __restrict__ enc,
                          const float* __restrict__ ali,
                          float* __restrict__ cpart) {
    int s = blockIdx.x;
    int n = blockIdx.y;
    int d0 = threadIdx.x * 2;
    const float* base = enc + ((size_t)n * TI + s * TCHUNK) * ED + d0;
    const float* ap = ali + n * TI + s * TCHUNK;
    float ax = 0.f, ay = 0.f;
#pragma unroll 4
    for (int t = 0; t < TCHUNK; ++t) {
        float a = ap[t];
        float2 v = *(const float2*)(base + (size_t)t * ED);
        ax = fmaf(a, v.x, ax);
        ay = fmaf(a, v.y, ay);
    }
    float2 r; r.x = ax; r.y = ay;
    *(float2*)&cpart[((size_t)(n * NSPLIT + s)) * ED + d0] = r;
}

// ---------------- Kernel 5: reduce ctx partials ----------------
__global__ void k_ctxred(const float* __restrict__ cpart, float* __restrict__ ctx) {
    int n = blockIdx.x;
    for (int d = threadIdx.x; d < ED; d += 256) {
        float sum = 0.f;
#pragma unroll
        for (int s = 0; s < NSPLIT; ++s) sum += cpart[((size_t)(n * NSPLIT + s)) * ED + d];
        ctx[(size_t)n * ED + d] = sum;
    }
}

extern "C" void kernel_launch(void* const* d_in, const int* in_sizes, int n_in,
                              void* d_out, int out_size, void* d_ws, size_t ws_size,
                              hipStream_t stream) {
    const float* enc_pad  = (const float*)d_in[0];
    const int*   enc_len  = (const int*)d_in[1];
    const float* dec_prev = (const float*)d_in[2];
    // d_in[3] = ali_prev (unused by reference)
    const float* W_enc    = (const float*)d_in[4];
    const float* b_enc    = (const float*)d_in[5];
    const float* W_dec    = (const float*)d_in[6];
    const float* w_v      = (const float*)d_in[7];

    float* out = (float*)d_out;
    float* ali = out;              // 64000 floats
    float* ctx = out + M_TOT;      // 16384 floats

    float* ws     = (float*)d_ws;
    float* db     = ws;                          // 32*512
    float* e_part = ws + NB * AD;                // 4*64000
    float* cpart  = e_part + 4 * M_TOT;          // 32*20*512
    size_t fp_floats = (size_t)NB * AD + 4 * M_TOT + (size_t)NB * NSPLIT * ED;  // 600064
    _Float16* X16 = (_Float16*)((char*)d_ws + fp_floats * 4);
    _Float16* W16 = X16 + (size_t)MT * KT * TILE_HALVES;
    size_t need = fp_floats * 4 + ((size_t)MT * KT + 32) * TILE_BYTES;
    bool big = ws_size >= need;

    hipLaunchKernelGGL(k_decdb, dim3(NB), dim3(256), 0, stream, dec_prev, W_dec, b_enc, db);
    if (big) {
        hipLaunchKernelGGL(k_convert, dim3(MT * KT + 32), dim3(256), 0, stream,
                           enc_pad, W_enc, X16, W16);
        hipLaunchKernelGGL(k_score, dim3(2016), dim3(256), 0, stream,
                           X16, W16, db, w_v, e_part);
    } else {
        hipLaunchKernelGGL(k_score_fb, dim3(MT, 4), dim3(256), 0, stream,
                           enc_pad, W_enc, db, w_v, e_part);
    }
    hipLaunchKernelGGL(k_softmax, dim3(NB), dim3(256), 0, stream, e_part, enc_len, ali);
    if (big) {
        hipLaunchKernelGGL(k_ctxpart16, dim3(NSPLIT, NB), dim3(256), 0, stream, X16, ali, cpart);
    } else {
        hipLaunchKernelGGL(k_ctxpart, dim3(NSPLIT, NB), dim3(256), 0, stream, enc_pad, ali, cpart);
    }
    hipLaunchKernelGGL(k_ctxred, dim3(NB), dim3(256), 0, stream, cpart, ctx);
}

// Round 3
// 138.864 us; speedup vs baseline: 1.0952x; 1.0583x over previous
//
#include <hip/hip_runtime.h>
#include <stdint.h>

// CtxAttention: additive attention (Bahdanau).
//   e[n,t]  = sum_a w_v[a] * tanh( enc_pad[n,t,:]·W_enc[a,:] + b_enc[a] + dec_prev[n,:]·W_dec[a,:] )
//   ali     = softmax_t(mask(e));  ctx[n,:] = sum_t ali[n,t] * enc_pad[n,t,:]
// Main GEMM (64000x512 @ 512x512) in f16 MFMA on pre-converted, pre-swizzled fp16 tiles.
// k_score256: 256x256 tile, 8 waves, double-buffered LDS, stage-before-compute (T3-min),
// setprio around MFMA clusters (T5), XOR-swizzled LDS (T2, both-sides with global_load_lds).

#define NB  32
#define TI  2000
#define ED  512
#define AD  512
#define M_TOT (NB * TI)          // 64000
#define NSPLIT 20
#define TCHUNK (TI / NSPLIT)     // 100
#define MT  500                  // 128-row m-tiles (convert granularity)
#define MT2 250                  // 256-row m-tiles (score granularity)
#define KT  8                    // k-tiles of 64
#define TILE_BYTES  16384        // 128 rows x 64 halves x 2B
#define TILE_HALVES 8192

using f16x8 = __attribute__((ext_vector_type(8))) _Float16;
using f32x4 = __attribute__((ext_vector_type(4))) float;

// swizzle within a 128x64-half tile; row r (0..127), byte-col c (16B aligned, 0..127)
__device__ __forceinline__ int swz(int r, int c) { return (r * 128 + c) ^ ((r & 7) << 4); }

#define GLD16(g, l)                                                     \
    __builtin_amdgcn_global_load_lds(                                   \
        (const __attribute__((address_space(1))) void*)(g),             \
        (__attribute__((address_space(3))) void*)(l), 16, 0, 0)

__device__ __forceinline__ float fast_tanh(float s) {
    s = fminf(fmaxf(s, -15.f), 15.f);
    float t = __expf(2.f * s);
    return __fdividef(t - 1.f, t + 1.f);
}

// ---------------- Kernel 0: convert enc_pad / W_enc -> tiled swizzled fp16; + fused decdb ----
// bx in [0,4000): X tile (mt = bx>>3, kt = bx&7); [4000,4032): W tile; [4032,4064): decdb row n.
__global__ void k_convert(const float* __restrict__ enc, const float* __restrict__ Wenc,
                          _Float16* __restrict__ X16, _Float16* __restrict__ W16,
                          const float* __restrict__ dec_prev, const float* __restrict__ W_dec,
                          const float* __restrict__ b_enc, float* __restrict__ db) {
    __shared__ float xd[ED];
    int bx = blockIdx.x;
    int tid = threadIdx.x;
    if (bx >= MT * KT + 32) {
        // ---- decdb: db[n][a] = dec_prev[n,:]·W_dec[a,:] + b_enc[a] ----
        int n = bx - (MT * KT + 32);
        for (int k = tid; k < ED; k += 256) xd[k] = dec_prev[n * ED + k];
        __syncthreads();
        for (int a = tid; a < AD; a += 256) {
            const float* wr = W_dec + (size_t)a * ED;
            float s = 0.f;
#pragma unroll 8
            for (int k = 0; k < ED; k += 4) {
                float4 w = *(const float4*)(wr + k);
                s += xd[k] * w.x + xd[k + 1] * w.y + xd[k + 2] * w.z + xd[k + 3] * w.w;
            }
            db[n * AD + a] = s + b_enc[a];
        }
        return;
    }
    const float* src;
    char* dstb;
    if (bx < MT * KT) {
        int mt = bx >> 3, kt = bx & 7;
        src  = enc + (size_t)mt * 128 * ED + kt * 64;
        dstb = (char*)(X16 + (size_t)bx * TILE_HALVES);
    } else {
        int wt = bx - MT * KT;
        int at = wt >> 3, kt = wt & 7;
        src  = Wenc + (size_t)at * 128 * ED + kt * 64;
        dstb = (char*)(W16 + (size_t)wt * TILE_HALVES);
    }
#pragma unroll
    for (int i = 0; i < 4; ++i) {
        int o  = i * 4096 + tid * 16;  // logical byte offset in tile
        int r  = o >> 7;               // row 0..127
        int c2 = o & 127;              // byte col (multiple of 16)
        const float* s = src + (size_t)r * ED + (c2 >> 1);
        float4 a = *(const float4*)s;
        float4 b = *(const float4*)(s + 4);
        f16x8 h;
        h[0] = (_Float16)a.x; h[1] = (_Float16)a.y; h[2] = (_Float16)a.z; h[3] = (_Float16)a.w;
        h[4] = (_Float16)b.x; h[5] = (_Float16)b.y; h[6] = (_Float16)b.z; h[7] = (_Float16)b.w;
        *(f16x8*)(dstb + swz(r, c2)) = h;
    }
}

// ---------------- standalone decdb (fallback path only) ----------------
__global__ void k_decdb(const float* __restrict__ dec_prev,
                        const float* __restrict__ W_dec,
                        const float* __restrict__ b_enc,
                        float* __restrict__ db) {
    int n = blockIdx.x;
    __shared__ float xd[ED];
    for (int k = threadIdx.x; k < ED; k += 256) xd[k] = dec_prev[n * ED + k];
    __syncthreads();
    for (int a = threadIdx.x; a < AD; a += 256) {
        const float* wr = W_dec + (size_t)a * ED;
        float s = 0.f;
#pragma unroll 8
        for (int k = 0; k < ED; k += 4) {
            float4 w = *(const float4*)(wr + k);
            s += xd[k] * w.x + xd[k + 1] * w.y + xd[k + 2] * w.z + xd[k + 3] * w.w;
        }
        db[n * AD + a] = s + b_enc[a];
    }
}

// ---------------- Kernel 2: fused score GEMM, 256x256 tile, 8 waves, dbuf ----------------
// grid 512: fid -> g=fid>>4, r=fid&15, at2=r>>3, mt2=g*8+(r&7).  (mt2,at2=0/1) are 8 apart
// in fid -> same XCD (round-robin) -> X16 L2 reuse.
__device__ __forceinline__ void stage_tiles(const char* xb, const char* wb,
                                            char* dA, char* dB, int kt, int o) {
    const char* xs = xb + kt * TILE_BYTES + o;
    const char* ws = wb + kt * TILE_BYTES + o;
    GLD16(xs,                           dA + o);
    GLD16(xs + 8192,                    dA + o + 8192);
    GLD16(xs + KT * TILE_BYTES,         dA + o + 16384);
    GLD16(xs + KT * TILE_BYTES + 8192,  dA + o + 24576);
    GLD16(ws,                           dB + o);
    GLD16(ws + 8192,                    dB + o + 8192);
    GLD16(ws + KT * TILE_BYTES,         dB + o + 16384);
    GLD16(ws + KT * TILE_BYTES + 8192,  dB + o + 24576);
}

__launch_bounds__(512, 2)
__global__ void k_score256(const _Float16* __restrict__ X16, const _Float16* __restrict__ W16,
                           const float* __restrict__ db, const float* __restrict__ wv,
                           float* __restrict__ e_part) {
    __shared__ alignas(16) char As0[32768];
    __shared__ alignas(16) char As1[32768];
    __shared__ alignas(16) char Bs0[32768];
    __shared__ alignas(16) char Bs1[32768];

    int fid = blockIdx.x;
    int g = fid >> 4, r = fid & 15;
    int at2 = r >> 3;
    int mt2 = g * 8 + (r & 7);
    if (mt2 >= MT2) return;

    const int tid  = threadIdx.x;
    const int lane = tid & 63;
    const int w    = tid >> 6;       // wave 0..7
    const int wm   = w >> 2;         // wave M-half (0..1): rows wm*128..+128
    const int wn   = w & 3;          // wave N-quarter (0..3): cols wn*64..+64
    const int m0   = mt2 * 256;
    const int a0   = at2 * 256;

    const char* xb = (const char*)X16 + (size_t)(mt2 * 2 * KT) * TILE_BYTES;
    const char* wb = (const char*)W16 + (size_t)(at2 * 2 * KT) * TILE_BYTES;

    const int lr    = lane & 15;
    const int lk2   = (lane >> 4) * 16;       // byte col of 8-half frag slice within 64-B k-slice... (within 128B row)
    const int wmoff = wm * 16384;
    const int wnoff = (wn >> 1) * 16384;
    const int wnrow = (wn & 1) * 64;
    const int o     = tid * 16;               // staging byte offset (linear, 0..8191)

    f32x4 acc[8][4];
#pragma unroll
    for (int rb = 0; rb < 8; ++rb)
#pragma unroll
        for (int cb = 0; cb < 4; ++cb) acc[rb][cb] = (f32x4){0.f, 0.f, 0.f, 0.f};

#define COMPUTE(sA, sB)                                                          \
    {                                                                            \
        _Pragma("unroll")                                                        \
        for (int kb = 0; kb < 2; ++kb) {                                         \
            f16x8 aF[8], bF[4];                                                  \
            _Pragma("unroll")                                                    \
            for (int rb = 0; rb < 8; ++rb)                                       \
                aF[rb] = *(const f16x8*)((sA) + wmoff + swz(rb * 16 + lr, kb * 64 + lk2)); \
            _Pragma("unroll")                                                    \
            for (int cb = 0; cb < 4; ++cb)                                       \
                bF[cb] = *(const f16x8*)((sB) + wnoff + swz(wnrow + cb * 16 + lr, kb * 64 + lk2)); \
            __builtin_amdgcn_s_setprio(1);                                       \
            _Pragma("unroll")                                                    \
            for (int rb = 0; rb < 8; ++rb)                                       \
                _Pragma("unroll")                                                \
                for (int cb = 0; cb < 4; ++cb)                                   \
                    acc[rb][cb] = __builtin_amdgcn_mfma_f32_16x16x32_f16(        \
                        aF[rb], bF[cb], acc[rb][cb], 0, 0, 0);                   \
            __builtin_amdgcn_s_setprio(0);                                       \
        }                                                                        \
    }

    // prologue + fully unrolled 8-tile double-buffered pipeline
    stage_tiles(xb, wb, As0, Bs0, 0, o); __syncthreads();
    stage_tiles(xb, wb, As1, Bs1, 1, o); COMPUTE(As0, Bs0); __syncthreads();
    stage_tiles(xb, wb, As0, Bs0, 2, o); COMPUTE(As1, Bs1); __syncthreads();
    stage_tiles(xb, wb, As1, Bs1, 3, o); COMPUTE(As0, Bs0); __syncthreads();
    stage_tiles(xb, wb, As0, Bs0, 4, o); COMPUTE(As1, Bs1); __syncthreads();
    stage_tiles(xb, wb, As1, Bs1, 5, o); COMPUTE(As0, Bs0); __syncthreads();
    stage_tiles(xb, wb, As0, Bs0, 6, o); COMPUTE(As1, Bs1); __syncthreads();
    stage_tiles(xb, wb, As1, Bs1, 7, o); COMPUTE(As0, Bs0); __syncthreads();
    COMPUTE(As1, Bs1); __syncthreads();
#undef COMPUTE

    // epilogue: rs = sum over 64 cols of w_v*tanh(acc+db); shfl-reduce 16 lanes;
    // cross-wave (4 N-quarters) reduce via e_red overlaid on As0 (idle now).
    float* e_red = (float*)As0;   // [4][256]
    const int lg = lane >> 4;
    float wvv[4];
#pragma unroll
    for (int cb = 0; cb < 4; ++cb) wvv[cb] = wv[a0 + wn * 64 + cb * 16 + lr];

#pragma unroll
    for (int rb = 0; rb < 8; ++rb) {
#pragma unroll
        for (int i = 0; i < 4; ++i) {
            int row_local = wm * 128 + rb * 16 + lg * 4 + i;  // C/D: row=(lane>>4)*4+reg
            int m = m0 + row_local;
            int n = m / TI;
            const float* dbp = db + (size_t)n * AD + a0 + wn * 64;
            float rs = 0.f;
#pragma unroll
            for (int cb = 0; cb < 4; ++cb) {
                float s = acc[rb][cb][i] + dbp[cb * 16 + lr];  // col = lane&15
                rs += fast_tanh(s) * wvv[cb];
            }
            rs += __shfl_xor(rs, 1);
            rs += __shfl_xor(rs, 2);
            rs += __shfl_xor(rs, 4);
            rs += __shfl_xor(rs, 8);
            if (lr == 0) e_red[wn * 256 + row_local] = rs;
        }
    }
    __syncthreads();
    if (tid < 256)
        e_part[(size_t)at2 * M_TOT + m0 + tid] =
            e_red[tid] + e_red[256 + tid] + e_red[512 + tid] + e_red[768 + tid];
}

// ---------------- fallback fp32 GEMM (convert-in-kernel) if ws too small ----------------
__launch_bounds__(256, 2)
__global__ void k_score_fb(const float* __restrict__ X, const float* __restrict__ W,
                           const float* __restrict__ db, const float* __restrict__ wv,
                           float* __restrict__ e_part) {
    __shared__ alignas(16) _Float16 Xs[128][72];
    __shared__ alignas(16) _Float16 Ws[128][72];
    __shared__ float e_red[2][128];

    const int tid = threadIdx.x, lane = tid & 63, wid = tid >> 6;
    const int wr = wid >> 1, wc = wid & 1;
    const int m0 = blockIdx.x * 128, a0 = blockIdx.y * 128;

    f32x4 acc[4][4];
#pragma unroll
    for (int rb = 0; rb < 4; ++rb)
#pragma unroll
        for (int cb = 0; cb < 4; ++cb) acc[rb][cb] = (f32x4){0.f, 0.f, 0.f, 0.f};

    const int lr = lane & 15;
    const int lk = (lane >> 4) << 3;

    for (int kt = 0; kt < ED; kt += 64) {
#pragma unroll
        for (int i = 0; i < 4; ++i) {
            int idx = tid + i * 256, r = idx >> 3, c = (idx & 7) << 3;
            const float* gx = X + (size_t)(m0 + r) * ED + kt + c;
            float4 x0 = *(const float4*)gx, x1 = *(const float4*)(gx + 4);
            f16x8 hx;
            hx[0] = (_Float16)x0.x; hx[1] = (_Float16)x0.y; hx[2] = (_Float16)x0.z; hx[3] = (_Float16)x0.w;
            hx[4] = (_Float16)x1.x; hx[5] = (_Float16)x1.y; hx[6] = (_Float16)x1.z; hx[7] = (_Float16)x1.w;
            *(f16x8*)&Xs[r][c] = hx;
            const float* gw = W + (size_t)(a0 + r) * ED + kt + c;
            float4 w0 = *(const float4*)gw, w1 = *(const float4*)(gw + 4);
            f16x8 hw;
            hw[0] = (_Float16)w0.x; hw[1] = (_Float16)w0.y; hw[2] = (_Float16)w0.z; hw[3] = (_Float16)w0.w;
            hw[4] = (_Float16)w1.x; hw[5] = (_Float16)w1.y; hw[6] = (_Float16)w1.z; hw[7] = (_Float16)w1.w;
            *(f16x8*)&Ws[r][c] = hw;
        }
        __syncthreads();
#pragma unroll
        for (int kb = 0; kb < 64; kb += 32) {
            f16x8 aF[4], bF[4];
#pragma unroll
            for (int rb = 0; rb < 4; ++rb) aF[rb] = *(const f16x8*)&Xs[wr * 64 + rb * 16 + lr][kb + lk];
#pragma unroll
            for (int cb = 0; cb < 4; ++cb) bF[cb] = *(const f16x8*)&Ws[wc * 64 + cb * 16 + lr][kb + lk];
#pragma unroll
            for (int rb = 0; rb < 4; ++rb)
#pragma unroll
                for (int cb = 0; cb < 4; ++cb)
                    acc[rb][cb] = __builtin_amdgcn_mfma_f32_16x16x32_f16(aF[rb], bF[cb], acc[rb][cb], 0, 0, 0);
        }
        __syncthreads();
    }

    const int lg = lane >> 4;
    float wvv[4];
#pragma unroll
    for (int cb = 0; cb < 4; ++cb) wvv[cb] = wv[a0 + wc * 64 + cb * 16 + lr];
#pragma unroll
    for (int rb = 0; rb < 4; ++rb) {
#pragma unroll
        for (int i = 0; i < 4; ++i) {
            int row_local = wr * 64 + rb * 16 + lg * 4 + i;
            int m = m0 + row_local;
            int n = m / TI;
            const float* dbp = db + (size_t)n * AD + a0 + wc * 64;
            float rs = 0.f;
#pragma unroll
            for (int cb = 0; cb < 4; ++cb) {
                float s = acc[rb][cb][i] + dbp[cb * 16 + lr];
                rs += fast_tanh(s) * wvv[cb];
            }
            rs += __shfl_xor(rs, 1);
            rs += __shfl_xor(rs, 2);
            rs += __shfl_xor(rs, 4);
            rs += __shfl_xor(rs, 8);
            if (lr == 0) e_red[wc][row_local] = rs;
        }
    }
    __syncthreads();
    if (tid < 128)
        e_part[(size_t)blockIdx.y * M_TOT + m0 + tid] = e_red[0][tid] + e_red[1][tid];
}

// ---------------- Kernel 3: masked softmax over t, per n ----------------
__global__ void k_softmax(const float* __restrict__ e_part,
                          const int* __restrict__ enc_len,
                          float* __restrict__ ali, int nparts) {
    int n = blockIdx.x;
    int len = enc_len[n];
    __shared__ float se[TI];
    __shared__ float redm[4];
    __shared__ float reds[4];
    int tid = threadIdx.x;
    int lane = tid & 63, wid = tid >> 6;

    for (int t = tid; t < TI; t += 256) {
        float s = 0.f;
        for (int p = 0; p < nparts; ++p) s += e_part[(size_t)p * M_TOT + n * TI + t];
        se[t] = s;
    }
    __syncthreads();

    float mx = -1e30f;
    for (int t = tid; t < len; t += 256) mx = fmaxf(mx, se[t]);
#pragma unroll
    for (int o = 32; o >= 1; o >>= 1) mx = fmaxf(mx, __shfl_xor(mx, o));
    if (lane == 0) redm[wid] = mx;
    __syncthreads();
    mx = fmaxf(fmaxf(redm[0], redm[1]), fmaxf(redm[2], redm[3]));

    float sm = 0.f;
    for (int t = tid; t < len; t += 256) {
        float ex = __expf(se[t] - mx);
        se[t] = ex;
        sm += ex;
    }
#pragma unroll
    for (int o = 32; o >= 1; o >>= 1) sm += __shfl_xor(sm, o);
    if (lane == 0) reds[wid] = sm;
    __syncthreads();
    float inv = 1.f / (reds[0] + reds[1] + reds[2] + reds[3]);

    for (int t = tid; t < TI; t += 256)
        ali[n * TI + t] = (t < len) ? se[t] * inv : 0.f;
}

// ---------------- Kernel 4a: ctx partials from fp16 tiled X16 ----------------
__global__ void k_ctxpart16(const _Float16* __restrict__ X16, const float* __restrict__ ali,
                            float* __restrict__ cpart) {
    int s = blockIdx.x, n = blockIdx.y;
    int tid = threadIdx.x;
    int sub = tid >> 6;            // t-phase 0..3
    int dc  = (tid & 63) * 8;      // 8 d-cols per thread
    int ktile = dc >> 6;
    int c2 = (dc & 63) * 2;
    float acc[8] = {0.f, 0.f, 0.f, 0.f, 0.f, 0.f, 0.f, 0.f};
    for (int t = s * TCHUNK + sub; t < (s + 1) * TCHUNK; t += 4) {
        int m = n * TI + t;
        int mt2 = m >> 7, r = m & 127;
        const char* p = (const char*)(X16 + (size_t)(mt2 * KT + ktile) * TILE_HALVES);
        f16x8 v = *(const f16x8*)(p + swz(r, c2));
        float a = ali[m];
#pragma unroll
        for (int j = 0; j < 8; ++j) acc[j] = fmaf(a, (float)v[j], acc[j]);
    }
    __shared__ float red[4][ED];
#pragma unroll
    for (int j = 0; j < 8; ++j) red[sub][dc + j] = acc[j];
    __syncthreads();
    if (sub == 0) {
#pragma unroll
        for (int j = 0; j < 8; ++j) {
            float sm = red[0][dc + j] + red[1][dc + j] + red[2][dc + j] + red[3][dc + j];
            cpart[((size_t)(n * NSPLIT + s)) * ED + dc + j] = sm;
        }
    }
}

// ---------------- Kernel 4b: fp32 ctx partials (fallback) ----------------
__global__ void k_ctxpart(const float* __restrict__ enc,
                          const float* __restrict__ ali,
                          float* __restrict__ cpart) {
    int s = blockIdx.x;
    int n = blockIdx.y;
    int d0 = threadIdx.x * 2;
    const float* base = enc + ((size_t)n * TI + s * TCHUNK) * ED + d0;
    const float* ap = ali + n * TI + s * TCHUNK;
    float ax = 0.f, ay = 0.f;
#pragma unroll 4
    for (int t = 0; t < TCHUNK; ++t) {
        float a = ap[t];
        float2 v = *(const float2*)(base + (size_t)t * ED);
        ax = fmaf(a, v.x, ax);
        ay = fmaf(a, v.y, ay);
    }
    float2 r; r.x = ax; r.y = ay;
    *(float2*)&cpart[((size_t)(n * NSPLIT + s)) * ED + d0] = r;
}

// ---------------- Kernel 5: reduce ctx partials ----------------
__global__ void k_ctxred(const float* __restrict__ cpart, float* __restrict__ ctx) {
    int n = blockIdx.x;
    for (int d = threadIdx.x; d < ED; d += 256) {
        float sum = 0.f;
#pragma unroll
        for (int s = 0; s < NSPLIT; ++s) sum += cpart[((size_t)(n * NSPLIT + s)) * ED + d];
        ctx[(size_t)n * ED + d] = sum;
    }
}

extern "C" void kernel_launch(void* const* d_in, const int* in_sizes, int n_in,
                              void* d_out, int out_size, void* d_ws, size_t ws_size,
                              hipStream_t stream) {
    const float* enc_pad  = (const float*)d_in[0];
    const int*   enc_len  = (const int*)d_in[1];
    const float* dec_prev = (const float*)d_in[2];
    // d_in[3] = ali_prev (unused by reference)
    const float* W_enc    = (const float*)d_in[4];
    const float* b_enc    = (const float*)d_in[5];
    const float* W_dec    = (const float*)d_in[6];
    const float* w_v      = (const float*)d_in[7];

    float* out = (float*)d_out;
    float* ali = out;              // 64000 floats
    float* ctx = out + M_TOT;      // 16384 floats

    float* ws     = (float*)d_ws;
    float* db     = ws;                          // 32*512
    float* e_part = ws + NB * AD;                // up to 4*64000
    float* cpart  = e_part + 4 * M_TOT;          // 32*20*512
    size_t fp_floats = (size_t)NB * AD + 4 * M_TOT + (size_t)NB * NSPLIT * ED;  // 600064
    _Float16* X16 = (_Float16*)((char*)d_ws + fp_floats * 4);
    _Float16* W16 = X16 + (size_t)MT * KT * TILE_HALVES;
    size_t need = fp_floats * 4 + ((size_t)MT * KT + 32) * TILE_BYTES;
    bool big = ws_size >= need;

    if (big) {
        hipLaunchKernelGGL(k_convert, dim3(MT * KT + 64), dim3(256), 0, stream,
                           enc_pad, W_enc, X16, W16, dec_prev, W_dec, b_enc, db);
        hipLaunchKernelGGL(k_score256, dim3(512), dim3(512), 0, stream,
                           X16, W16, db, w_v, e_part);
        hipLaunchKernelGGL(k_softmax, dim3(NB), dim3(256), 0, stream, e_part, enc_len, ali, 2);
        hipLaunchKernelGGL(k_ctxpart16, dim3(NSPLIT, NB), dim3(256), 0, stream, X16, ali, cpart);
    } else {
        hipLaunchKernelGGL(k_decdb, dim3(NB), dim3(256), 0, stream, dec_prev, W_dec, b_enc, db);
        hipLaunchKernelGGL(k_score_fb, dim3(MT, 4), dim3(256), 0, stream,
                           enc_pad, W_enc, db, w_v, e_part);
        hipLaunchKernelGGL(k_softmax, dim3(NB), dim3(256), 0, stream, e_part, enc_len, ali, 4);
        hipLaunchKernelGGL(k_ctxpart, dim3(NSPLIT, NB), dim3(256), 0, stream, enc_pad, ali, cpart);
    }
    hipLaunchKernelGGL(k_ctxred, dim3(NB), dim3(256), 0, stream, cpart, ctx);
}